// Round 4
// baseline (742.356 us; speedup 1.0000x reference)
//
#include <hip/hip_runtime.h>
#include <hip/hip_bf16.h>

#define T_STEPS 2048
#define BATCH 16
#define DIM 1024
#define NDIM 64
#define M_TOTAL (T_STEPS * BATCH)  // 32768
#define STRIDE (BATCH * NDIM)      // floats per timestep = 1024
#define CH 32                      // recurrence chunk (timesteps per LDS buffer)

typedef __attribute__((ext_vector_type(8))) short bf16x8;
typedef __attribute__((ext_vector_type(4))) float f32x4;
typedef __attribute__((ext_vector_type(2))) float f32x2;

__device__ inline unsigned pk_bf(float lo, float hi) {
    __hip_bfloat162 h = __float22bfloat162_rn(float2{lo, hi});
    return *(unsigned*)&h;  // v_cvt_pk_bf16_f32
}

template <int CTRL>
__device__ inline float dpp_add(float x) {
    int v = __builtin_amdgcn_update_dpp(0, __float_as_int(x), CTRL, 0xF, 0xF, true);
    return x + __int_as_float(v);
}
// full sum across 16-lane rows
__device__ inline float red16(float x) {
    x = dpp_add<0xB1>(x);   // quad_perm xor1
    x = dpp_add<0x4E>(x);   // quad_perm xor2
    x = dpp_add<0x141>(x);  // row_half_mirror (xor4)
    x = dpp_add<0x140>(x);  // row_mirror (xor8)
    return x;
}
// full sum across aligned 8-lane groups
__device__ inline float red8(float x) {
    x = dpp_add<0xB1>(x);   // xor1
    x = dpp_add<0x4E>(x);   // xor2
    x = dpp_add<0x141>(x);  // xor4 within 8-lane half
    return x;
}
__device__ inline float fast_sigmoid(float z) {
    return __builtin_amdgcn_rcpf(1.f + __expf(-z));
}

#define AS1 __attribute__((address_space(1)))
#define AS3 __attribute__((address_space(3)))
__device__ inline void gl_lds16(const float* g, float* l) {
    __builtin_amdgcn_global_load_lds((const AS1 unsigned*)g, (AS3 unsigned*)l, 16, 0, 0);
}
__device__ inline void gl_lds4(const float* g, float* l) {
    __builtin_amdgcn_global_load_lds((const AS1 unsigned*)g, (AS3 unsigned*)l, 4, 0, 0);
}
#define WAIT_VM0 do { __builtin_amdgcn_s_waitcnt(0x0F70); asm volatile("" ::: "memory"); } while (0)

// ---------------- W prepack: fp32 [4][64][1024] -> bf16 [256][1024] ----------------
__global__ __launch_bounds__(256) void pack_w(
    const float* __restrict__ Wk, const float* __restrict__ Wv,
    const float* __restrict__ Wq, const float* __restrict__ Wa,
    unsigned short* __restrict__ Wb) {
    int n = blockIdx.x;  // 0..255
    int sel = n >> 6;
    const float* W = (sel == 0) ? Wk : (sel == 1) ? Wv : (sel == 2) ? Wq : Wa;
    int k4 = threadIdx.x * 4;
    float4 f = *(const float4*)(W + (size_t)(n & 63) * DIM + k4);
    uint2 u;
    u.x = pk_bf(f.x, f.y);
    u.y = pk_bf(f.z, f.w);
    *(uint2*)(Wb + (size_t)n * DIM + k4) = u;
}

// ---------------- projection: zero-LDS register GEMM ----------------
// 256 blocks x 4 waves; wave computes C[32, 256]. A direct from global x (fp32->bf16
// in regs, 4 pk_bf per frag), B direct from prepacked bf16 W. No LDS, no barriers.
__global__ __launch_bounds__(256, 2) void proj_kernel(
    const float* __restrict__ x, const unsigned short* __restrict__ Wb,
    const float* __restrict__ ba,
    float* __restrict__ outBase, float* __restrict__ kqOut) {
    int tid = threadIdx.x;
    int wv = tid >> 6;
    int lane = tid & 63;
    int lrow = lane & 15;
    int quad = lane >> 4;
    int m0 = blockIdx.x * 128 + wv * 32;

    f32x4 acc[2][16];
#pragma unroll
    for (int a = 0; a < 2; a++)
#pragma unroll
        for (int b = 0; b < 16; b++) acc[a][b] = (f32x4)(0.f);

    const float* xr0 = x + (size_t)(m0 + lrow) * DIM + quad * 8;
    const float* xr1 = xr0 + (size_t)16 * DIM;
    const unsigned short* wb = Wb + (size_t)lrow * DIM + quad * 8;

    for (int k0 = 0; k0 < DIM; k0 += 32) {
        float4 a00 = ((const float4*)(xr0 + k0))[0];
        float4 a01 = ((const float4*)(xr0 + k0))[1];
        float4 a10 = ((const float4*)(xr1 + k0))[0];
        float4 a11 = ((const float4*)(xr1 + k0))[1];
        unsigned p0[4], p1[4];
        p0[0] = pk_bf(a00.x, a00.y); p0[1] = pk_bf(a00.z, a00.w);
        p0[2] = pk_bf(a01.x, a01.y); p0[3] = pk_bf(a01.z, a01.w);
        p1[0] = pk_bf(a10.x, a10.y); p1[1] = pk_bf(a10.z, a10.w);
        p1[2] = pk_bf(a11.x, a11.y); p1[3] = pk_bf(a11.z, a11.w);
        bf16x8 af0 = *(bf16x8*)&p0[0];
        bf16x8 af1 = *(bf16x8*)&p1[0];
#pragma unroll
        for (int bt = 0; bt < 16; bt++) {
            bf16x8 bfr = *(const bf16x8*)(wb + (size_t)(bt * 16) * DIM + k0);
            acc[0][bt] = __builtin_amdgcn_mfma_f32_16x16x32_bf16(af0, bfr, acc[0][bt], 0, 0, 0);
            acc[1][bt] = __builtin_amdgcn_mfma_f32_16x16x32_bf16(af1, bfr, acc[1][bt], 0, 0, 0);
        }
    }

    // fold +b_alpha into the alpha projection (bt 12..15)
#pragma unroll
    for (int bt = 12; bt < 16; bt++) {
        float bav = ba[(bt - 12) * 16 + lrow];
#pragma unroll
        for (int rt = 0; rt < 2; rt++)
#pragma unroll
            for (int reg = 0; reg < 4; reg++) acc[rt][bt][reg] += bav;
    }
    // stores: C/D layout col = lane&15, row = quad*4 + reg  [m89-verified]
    const size_t per = (size_t)M_TOTAL * NDIM;
#pragma unroll
    for (int rt = 0; rt < 2; rt++)
#pragma unroll
        for (int bt = 0; bt < 16; bt++) {
            int n = bt * 16 + lrow;
            float* outW = outBase + (size_t)(n >> 6) * per + (n & 63);
#pragma unroll
            for (int reg = 0; reg < 4; reg++) {
                int m = m0 + rt * 16 + quad * 4 + reg;
                outW[(size_t)m * NDIM] = acc[rt][bt][reg];
            }
        }
    // kq[m] = K[m,:].Q[m,:]  (K tiles 0..3, Q tiles 8..11)
#pragma unroll
    for (int rt = 0; rt < 2; rt++)
#pragma unroll
        for (int reg = 0; reg < 4; reg++) {
            float p = acc[rt][0][reg] * acc[rt][8][reg] + acc[rt][1][reg] * acc[rt][9][reg] +
                      acc[rt][2][reg] * acc[rt][10][reg] + acc[rt][3][reg] * acc[rt][11][reg];
            p = red16(p);
            if (lrow == 0) kqOut[m0 + rt * 16 + quad * 4 + reg] = p;
        }
}

// ---------------- recurrence: 8 lanes/row, packed fp32, LDS double-buffer ----------------
// grid (8 row-groups, 16 batches) x 64; lane = rg*8+c; row i = g*8+rg, cols c*8..+7
__global__ __launch_bounds__(64, 1) void recur_kernel(
    const float* __restrict__ Kp, const float* __restrict__ Vp,
    const float* __restrict__ Qp, const float* __restrict__ Ap,
    const float* __restrict__ KQp, const float* __restrict__ S0,
    const float* __restrict__ d_alpha, float* __restrict__ out,
    float* __restrict__ Sout) {
    __shared__ float Kl[2][CH][64];   // 16 KB
    __shared__ float Ql[2][CH][64];   // 16 KB
    __shared__ float VAl[2][CH][16];  // 4 KB ([t][0..7]=v rows, [t][8..15]=a rows)
    __shared__ float KQl[2][64];      // 0.5 KB (only [0..31] used)

    int b = blockIdx.y;
    int g = blockIdx.x;     // 0..7
    int lane = threadIdx.x;
    int rg = lane >> 3;     // 0..7
    int c = lane & 7;
    int i = g * 8 + rg;
    int c8 = c * 8;

    const float* sp = S0 + ((size_t)b * NDIM + i) * NDIM + c8;
    float4 sA = ((const float4*)sp)[0], sB = ((const float4*)sp)[1];
    f32x2 s0 = {sA.x, sA.y}, s1 = {sA.z, sA.w}, s2 = {sB.x, sB.y}, s3 = {sB.z, sB.w};
    float da = d_alpha[i];

    // staging bases (lane roles for staging differ from compute roles)
    const float* Kbase = Kp + (size_t)b * NDIM + (size_t)(lane >> 4) * STRIDE + (lane & 15) * 4;
    const float* Qbase = Qp + (size_t)b * NDIM + (size_t)(lane >> 4) * STRIDE + (lane & 15) * 4;
    // VA: lane L -> step t0+(L>>2); (L&2)? a : v ; rows g*8 + (L&1)*4 ..+3
    const float* VAbase = ((lane & 2) ? Ap : Vp) + (size_t)b * NDIM + g * 8 + (lane & 1) * 4 +
                          (size_t)(lane >> 2) * STRIDE;
    const float* KQbase = KQp + b + (size_t)(lane & 31) * BATCH;

    auto load_chunk = [&](int t0, int buf) {
#pragma unroll
        for (int j = 0; j < 8; ++j) {
            gl_lds16(Kbase + (size_t)(t0 + j * 4) * STRIDE, &Kl[buf][j * 4][0]);
            gl_lds16(Qbase + (size_t)(t0 + j * 4) * STRIDE, &Ql[buf][j * 4][0]);
        }
        gl_lds16(VAbase + (size_t)t0 * STRIDE, &VAl[buf][0][0]);
        gl_lds16(VAbase + (size_t)(t0 + 16) * STRIDE, &VAl[buf][16][0]);
        gl_lds4(KQbase + (size_t)t0 * BATCH, &KQl[buf][0]);
    };

    load_chunk(0, 0);
    WAIT_VM0;

    float* ob = out + (size_t)b * NDIM + i;

    for (int j = 0; j < T_STEPS / CH; ++j) {
        int cb = j & 1;
        if (j + 1 < T_STEPS / CH) load_chunk((j + 1) * CH, cb ^ 1);

        const float* Kb = &Kl[cb][0][0];
        const float* Qb = &Ql[cb][0][0];
        const float* Vb = &VAl[cb][0][0];
        const float* Qk = &KQl[cb][0];

#pragma unroll
        for (int tl = 0; tl < CH; ++tl) {
            const f32x2* kp2 = (const f32x2*)(Kb + tl * 64 + c8);
            f32x2 k0 = kp2[0], k1 = kp2[1], k2 = kp2[2], k3 = kp2[3];
            const f32x2* qp2 = (const f32x2*)(Qb + tl * 64 + c8);
            f32x2 q0 = qp2[0], q1 = qp2[1], q2 = qp2[2], q3 = qp2[3];
            float v = Vb[tl * 16 + rg];
            float aa = Vb[tl * 16 + 8 + rg];  // includes b_alpha
            float kq = Qk[tl];

            f32x2 pk_ = (k0 * s0 + k1 * s1) + (k2 * s2 + k3 * s3);
            f32x2 pq_ = (q0 * s0 + q1 * s1) + (q2 * s2 + q3 * s3);
            float rk = red8(pk_.x + pk_.y);
            float rq = red8(pq_.x + pq_.y);

            float alpha = fast_sigmoid(fmaf(da, rk, aa));
            float oma = 1.f - alpha;

            // s = w + alpha*(s - w), w = v*k  (sub overlaps the sigmoid chain)
            f32x2 w0 = v * k0, w1 = v * k1, w2 = v * k2, w3 = v * k3;
            s0 = w0 + alpha * (s0 - w0);
            s1 = w1 + alpha * (s1 - w1);
            s2 = w2 + alpha * (s2 - w2);
            s3 = w3 + alpha * (s3 - w3);

            // out = S_new.q = alpha*rq + (1-alpha)*v*kq  (exact)
            float o = fmaf(alpha, rq, oma * v * kq);
            float ov = o * o * fast_sigmoid(o);
            if (c == 0) ob[(size_t)(j * CH + tl) * STRIDE] = ov;
        }
        WAIT_VM0;  // next chunk staged a full chunk ago
    }

    float* so = Sout + ((size_t)b * NDIM + i) * NDIM + c8;
    ((float4*)so)[0] = float4{s0.x, s0.y, s1.x, s1.y};
    ((float4*)so)[1] = float4{s2.x, s2.y, s3.x, s3.y};
}

extern "C" void kernel_launch(void* const* d_in, const int* in_sizes, int n_in,
                              void* d_out, int out_size, void* d_ws, size_t ws_size,
                              hipStream_t stream) {
    const float* x  = (const float*)d_in[0];
    const float* S0 = (const float*)d_in[1];
    const float* Wk = (const float*)d_in[2];
    const float* Wv = (const float*)d_in[3];
    const float* Wq = (const float*)d_in[4];
    const float* Wa = (const float*)d_in[5];
    const float* da = (const float*)d_in[6];
    const float* ba = (const float*)d_in[7];

    float* out = (float*)d_out;
    float* Sout = out + (size_t)T_STEPS * BATCH * NDIM;

    const size_t per = (size_t)M_TOTAL * NDIM;
    float* proj = (float*)d_ws;          // 4*per floats = 33.55 MB
    float* Kp = proj;
    float* Vp = proj + per;
    float* Qp = proj + 2 * per;
    float* Ap = proj + 3 * per;
    float* kq = proj + 4 * per;          // 128 KB
    unsigned short* Wb = (unsigned short*)(kq + M_TOTAL);  // 512 KB

    pack_w<<<dim3(256), dim3(256), 0, stream>>>(Wk, Wv, Wq, Wa, Wb);
    proj_kernel<<<dim3(M_TOTAL / 128), dim3(256), 0, stream>>>(x, Wb, ba, proj, kq);
    recur_kernel<<<dim3(8, BATCH), dim3(64), 0, stream>>>(Kp, Vp, Qp, Ap, kq, S0, da, out, Sout);
}

// Round 5
// 493.944 us; speedup vs baseline: 1.5029x; 1.5029x over previous
//
#include <hip/hip_runtime.h>
#include <hip/hip_bf16.h>

#define T_STEPS 2048
#define BATCH 16
#define DIM 1024
#define NDIM 64
#define M_TOTAL (T_STEPS * BATCH)  // 32768
#define STRIDE (BATCH * NDIM)      // floats per timestep in Kp/Qp = 1024
#define CH 32                      // recurrence chunk (timesteps per LDS buffer)

typedef __attribute__((ext_vector_type(8))) short bf16x8;
typedef __attribute__((ext_vector_type(4))) float f32x4;
typedef __attribute__((ext_vector_type(2))) float f32x2;

__device__ inline unsigned pk_bf(float lo, float hi) {
    __hip_bfloat162 h = __float22bfloat162_rn(float2{lo, hi});
    return *(unsigned*)&h;  // v_cvt_pk_bf16_f32
}

template <int CTRL>
__device__ inline float dpp_add(float x) {
    int v = __builtin_amdgcn_update_dpp(0, __float_as_int(x), CTRL, 0xF, 0xF, true);
    return x + __int_as_float(v);
}
// full sum across contiguous 16-lane rows (result in all 16 lanes)
__device__ inline float red16(float x) {
    x = dpp_add<0xB1>(x);   // quad_perm xor1
    x = dpp_add<0x4E>(x);   // quad_perm xor2
    x = dpp_add<0x141>(x);  // row_half_mirror (xor4)
    x = dpp_add<0x140>(x);  // row_mirror (xor8)
    return x;
}
__device__ inline float fast_sigmoid(float z) {
    return __builtin_amdgcn_rcpf(1.f + __expf(-z));
}

#define AS1 __attribute__((address_space(1)))
#define AS3 __attribute__((address_space(3)))
__device__ inline void gl_lds16(const float* g, float* l) {
    __builtin_amdgcn_global_load_lds((const AS1 unsigned*)g, (AS3 unsigned*)l, 16, 0, 0);
}
__device__ inline void gl_lds16s(const unsigned short* g, unsigned short* l) {
    __builtin_amdgcn_global_load_lds((const AS1 unsigned*)g, (AS3 unsigned*)l, 16, 0, 0);
}
__device__ inline void gl_lds4(const float* g, float* l) {
    __builtin_amdgcn_global_load_lds((const AS1 unsigned*)g, (AS3 unsigned*)l, 4, 0, 0);
}
#define WAIT_VM0 do { __builtin_amdgcn_s_waitcnt(0x0F70); asm volatile("" ::: "memory"); } while (0)

// ---------------- W prepack: fp32 -> bf16, row order [K, Q, V, A] ----------------
__global__ __launch_bounds__(256) void pack_w(
    const float* __restrict__ Wk, const float* __restrict__ Wq,
    const float* __restrict__ Wv, const float* __restrict__ Wa,
    unsigned short* __restrict__ Wb) {
    int n = blockIdx.x;  // 0..255
    int sel = n >> 6;
    const float* W = (sel == 0) ? Wk : (sel == 1) ? Wq : (sel == 2) ? Wv : Wa;
    int k4 = threadIdx.x * 4;
    float4 f = *(const float4*)(W + (size_t)(n & 63) * DIM + k4);
    uint2 u;
    u.x = pk_bf(f.x, f.y);
    u.y = pk_bf(f.z, f.w);
    *(uint2*)(Wb + (size_t)n * DIM + k4) = u;
}

// ---------------- projection: m97-style 128x128 tile, global_load_lds staging ----------------
// grid (256 m-tiles, 2 n-tiles) x 256 threads = 512 blocks (2/CU). BK=64, 16 k-iters.
// A staged fp32 (converted at frag build), B staged pre-packed bf16.
// n-tile0 = [K|Q], n-tile1 = [V|A]; V/A written interleaved to VAi; b_alpha folded into A.
__global__ __launch_bounds__(256, 2) void proj_kernel(
    const float* __restrict__ x, const unsigned short* __restrict__ Wb,
    const float* __restrict__ ba, float* __restrict__ Kp, float* __restrict__ Qp,
    float* __restrict__ VAi) {
    __shared__ float sA[128 * 64];            // 32 KB fp32
    __shared__ unsigned short sB[128 * 64];   // 16 KB bf16

    const int m0 = blockIdx.x * 128;
    const int ntile = blockIdx.y;
    const int tid = threadIdx.x;
    const int wv = tid >> 6, lane = tid & 63, lrow = lane & 15, quad = lane >> 4;
    const int wm = wv & 1, wn = wv >> 1;   // wave = (m-half, n-half) of 128x128 tile

    f32x4 acc[4][4];
#pragma unroll
    for (int a = 0; a < 4; a++)
#pragma unroll
        for (int b = 0; b < 4; b++) acc[a][b] = (f32x4)(0.f);

    // staging bases: lane-contiguous LDS dest (wave-uniform base + lane*16)
    const float* xg = x + (size_t)(m0 + (tid >> 4)) * DIM + (tid & 15) * 4;
    const unsigned short* wg = Wb + (size_t)(ntile * 128 + (tid >> 3)) * DIM + (tid & 7) * 8;

    for (int it = 0; it < 16; ++it) {
        const int k0 = it * 64;
        __syncthreads();  // previous iteration's frag reads done
#pragma unroll
        for (int j = 0; j < 8; ++j)  // A: 128x64 fp32 = 32 KB
            gl_lds16(xg + (size_t)(16 * j) * DIM + k0, &sA[(tid + 256 * j) * 4]);
#pragma unroll
        for (int j = 0; j < 4; ++j)  // B: 128x64 bf16 = 16 KB
            gl_lds16s(wg + (size_t)(32 * j) * DIM + k0, &sB[(tid + 256 * j) * 8]);
        WAIT_VM0;
        __syncthreads();

#pragma unroll
        for (int ks = 0; ks < 2; ++ks) {
            bf16x8 af[4];
#pragma unroll
            for (int mt = 0; mt < 4; ++mt) {
                const float* pa = &sA[(wm * 64 + mt * 16 + lrow) * 64 + ks * 32 + quad * 8];
                float4 lo = ((const float4*)pa)[0], hi = ((const float4*)pa)[1];
                unsigned pk[4] = {pk_bf(lo.x, lo.y), pk_bf(lo.z, lo.w),
                                  pk_bf(hi.x, hi.y), pk_bf(hi.z, hi.w)};
                af[mt] = *(bf16x8*)pk;
            }
#pragma unroll
            for (int nt = 0; nt < 4; ++nt) {
                bf16x8 bfr = *(const bf16x8*)&sB[(wn * 64 + nt * 16 + lrow) * 64 + ks * 32 + quad * 8];
#pragma unroll
                for (int mt = 0; mt < 4; ++mt)
                    acc[mt][nt] = __builtin_amdgcn_mfma_f32_16x16x32_bf16(af[mt], bfr, acc[mt][nt], 0, 0, 0);
            }
        }
    }

    // epilogue: C/D layout col = lane&15, row = quad*4 + reg  [m89-verified]
    const int g2 = ntile * 2 + wn;  // 0=K 1=Q 2=V 3=A
    float bav[4];
    if (g2 == 3) {
#pragma unroll
        for (int nt = 0; nt < 4; ++nt) bav[nt] = ba[nt * 16 + lrow];
    }
#pragma unroll
    for (int mt = 0; mt < 4; ++mt)
#pragma unroll
        for (int nt = 0; nt < 4; ++nt) {
            int col = nt * 16 + lrow;
#pragma unroll
            for (int reg = 0; reg < 4; ++reg) {
                int m = m0 + wm * 64 + mt * 16 + quad * 4 + reg;
                float vvv = acc[mt][nt][reg];
                if (g2 == 0) Kp[(size_t)m * 64 + col] = vvv;
                else if (g2 == 1) Qp[(size_t)m * 64 + col] = vvv;
                else if (g2 == 2) VAi[(size_t)m * 128 + col * 2] = vvv;
                else VAi[(size_t)m * 128 + col * 2 + 1] = vvv + bav[nt];
            }
        }
}

// ---------------- kq[m] = K[m,:] . Q[m,:] ----------------
__global__ __launch_bounds__(256) void kq_kernel(
    const float* __restrict__ Kp, const float* __restrict__ Qp, float* __restrict__ kq) {
    int m = blockIdx.x * 16 + (threadIdx.x >> 4);
    int c = threadIdx.x & 15;
    float4 k = *(const float4*)(Kp + (size_t)m * 64 + c * 4);
    float4 q = *(const float4*)(Qp + (size_t)m * 64 + c * 4);
    float p = k.x * q.x + k.y * q.y + k.z * q.z + k.w * q.w;
    p = red16(p);
    if (c == 0) kq[m] = p;
}

// ---------------- recurrence ----------------
// grid (16 row-groups, 16 batches) x 64; lane = r*16+c; row i = g*4+r, cols c*4..+3
__global__ __launch_bounds__(64, 1) void recur_kernel(
    const float* __restrict__ Kp, const float* __restrict__ Qp,
    const float* __restrict__ VAi, const float* __restrict__ KQp,
    const float* __restrict__ S0, const float* __restrict__ d_alpha,
    float* __restrict__ out, float* __restrict__ Sout) {
    __shared__ float Kl[2][CH][64];   // 16 KB
    __shared__ float Ql[2][CH][64];   // 16 KB
    __shared__ float VAl[2][CH][8];   // 2 KB: [t] = v0,a0,v1,a1,v2,a2,v3,a3 (rows g*4..+3)
    __shared__ float KQl[2][64];      // 0.5 KB (only [0..31] used)
    __shared__ float Ol[CH][4];       // per-chunk output staging

    int b = blockIdx.y, g = blockIdx.x, lane = threadIdx.x;
    int r = lane >> 4, c = lane & 15, i = g * 4 + r, c4 = c * 4;

    float4 sv = *(const float4*)(S0 + ((size_t)b * NDIM + i) * NDIM + c4);
    f32x2 s01 = {sv.x, sv.y}, s23 = {sv.z, sv.w};
    float da = d_alpha[i];

    const float* Kbase = Kp + (size_t)b * NDIM + (size_t)(lane >> 4) * STRIDE + (lane & 15) * 4;
    const float* Qbase = Qp + (size_t)b * NDIM + (size_t)(lane >> 4) * STRIDE + (lane & 15) * 4;
    const float* VAbase = VAi + (size_t)b * 128 + g * 8 + (lane & 1) * 4 + (size_t)(lane >> 1) * 2048;
    const float* KQbase = KQp + b + (size_t)(lane & 31) * BATCH;

    auto load_chunk = [&](int t0, int buf) {
#pragma unroll
        for (int j = 0; j < 8; ++j) {
            gl_lds16(Kbase + (size_t)(t0 + j * 4) * STRIDE, &Kl[buf][j * 4][0]);
            gl_lds16(Qbase + (size_t)(t0 + j * 4) * STRIDE, &Ql[buf][j * 4][0]);
        }
        gl_lds16(VAbase + (size_t)t0 * 2048, &VAl[buf][0][0]);
        gl_lds4(KQbase + (size_t)t0 * BATCH, &KQl[buf][0]);
    };

    load_chunk(0, 0);
    WAIT_VM0;

    // depth-2 LDS->reg pipeline
    f32x2 k01[2], k23[2], q01[2], q23[2], va[2];
    float kqv[2];
    {
        const float* Kb = &Kl[0][0][0];
        const float* Qb = &Ql[0][0][0];
#pragma unroll
        for (int u = 0; u < 2; ++u) {
            f32x4 kk = *(const f32x4*)(Kb + u * 64 + c4);
            f32x4 qq = *(const f32x4*)(Qb + u * 64 + c4);
            k01[u] = kk.lo; k23[u] = kk.hi;
            q01[u] = qq.lo; q23[u] = qq.hi;
            va[u] = *(const f32x2*)&VAl[0][u][r * 2];
            kqv[u] = KQl[0][u];
        }
    }

    for (int j = 0; j < T_STEPS / CH; ++j) {
        int cb = j & 1;
        if (j + 1 < T_STEPS / CH) load_chunk((j + 1) * CH, cb ^ 1);

        const float* Kb = &Kl[cb][0][0];
        const float* Qb = &Ql[cb][0][0];
        const float* Vb = &VAl[cb][0][0];
        const float* Qk = &KQl[cb][0];

#pragma unroll
        for (int tl = 0; tl < CH; ++tl) {
            int sl = tl & 1;
            f32x2 k0v = k01[sl], k1v = k23[sl], q0v = q01[sl], q1v = q23[sl];
            f32x2 vva = va[sl];
            float kq = kqv[sl];
            if (tl < CH - 2) {
                f32x4 kk = *(const f32x4*)(Kb + (tl + 2) * 64 + c4);
                f32x4 qq = *(const f32x4*)(Qb + (tl + 2) * 64 + c4);
                k01[sl] = kk.lo; k23[sl] = kk.hi;
                q01[sl] = qq.lo; q23[sl] = qq.hi;
                va[sl] = *(const f32x2*)&Vb[(tl + 2) * 8 + r * 2];
                kqv[sl] = Qk[tl + 2];
            }

            f32x2 pk_ = k0v * s01;
            pk_ = k1v * s23 + pk_;
            f32x2 pq_ = q0v * s01;
            pq_ = q1v * s23 + pq_;
            float rk = red16(pk_.x + pk_.y);
            float rq = red16(pq_.x + pq_.y);

            float v = vva.x;
            f32x2 w01 = v * k0v, w23 = v * k1v;       // pre-alpha
            f32x2 d01 = s01 - w01, d23 = s23 - w23;   // pre-alpha

            float alpha = fast_sigmoid(fmaf(da, rk, vva.y));  // vva.y includes b_alpha
            f32x2 a2 = {alpha, alpha};
            s01 = w01 + a2 * d01;   // s = w + alpha*(s-w)
            s23 = w23 + a2 * d23;

            float u1 = (1.f - alpha) * v;
            float o = fmaf(alpha, rq, u1 * kq);   // S_new.q = alpha*(S_old.q) + u1*(k.q)
            float ov = o * o * fast_sigmoid(o);
            if (c == 0) Ol[tl][r] = ov;
        }
        WAIT_VM0;  // chunk j+1 staged long ago; also retires old output stores

        if (lane < 32) {  // dump chunk outputs: lane = local t, 4 rows as float4
            float4 t4 = *(const float4*)&Ol[lane][0];
            *(float4*)(out + ((size_t)(j * CH + lane) * BATCH + b) * NDIM + g * 4) = t4;
        }

        if (j + 1 < T_STEPS / CH) {  // preload pipeline for next chunk
            int nb = cb ^ 1;
            const float* Kn = &Kl[nb][0][0];
            const float* Qn = &Ql[nb][0][0];
#pragma unroll
            for (int u = 0; u < 2; ++u) {
                f32x4 kk = *(const f32x4*)(Kn + u * 64 + c4);
                f32x4 qq = *(const f32x4*)(Qn + u * 64 + c4);
                k01[u] = kk.lo; k23[u] = kk.hi;
                q01[u] = qq.lo; q23[u] = qq.hi;
                va[u] = *(const f32x2*)&VAl[nb][u][r * 2];
                kqv[u] = KQl[nb][u];
            }
        }
    }

    float* so = Sout + ((size_t)b * NDIM + i) * NDIM + c4;
    *(float4*)so = float4{s01.x, s01.y, s23.x, s23.y};
}

extern "C" void kernel_launch(void* const* d_in, const int* in_sizes, int n_in,
                              void* d_out, int out_size, void* d_ws, size_t ws_size,
                              hipStream_t stream) {
    const float* x  = (const float*)d_in[0];
    const float* S0 = (const float*)d_in[1];
    const float* Wk = (const float*)d_in[2];
    const float* Wv = (const float*)d_in[3];
    const float* Wq = (const float*)d_in[4];
    const float* Wa = (const float*)d_in[5];
    const float* da = (const float*)d_in[6];
    const float* ba = (const float*)d_in[7];

    float* out = (float*)d_out;
    float* Sout = out + (size_t)T_STEPS * BATCH * NDIM;

    const size_t per = (size_t)M_TOTAL * NDIM;
    float* Kp  = (float*)d_ws;           // per floats
    float* Qp  = Kp + per;               // per
    float* VAi = Qp + per;               // 2*per (v,a interleaved per row)
    float* kq  = VAi + 2 * per;          // M_TOTAL
    unsigned short* Wb = (unsigned short*)(kq + M_TOTAL);  // 512 KB bf16

    pack_w<<<dim3(256), dim3(256), 0, stream>>>(Wk, Wq, Wv, Wa, Wb);
    proj_kernel<<<dim3(M_TOTAL / 128, 2), dim3(256), 0, stream>>>(x, Wb, ba, Kp, Qp, VAi);
    kq_kernel<<<dim3(M_TOTAL / 16), dim3(256), 0, stream>>>(Kp, Qp, kq);
    recur_kernel<<<dim3(16, BATCH), dim3(64), 0, stream>>>(Kp, Qp, VAi, kq, S0, da, out, Sout);
}